// Round 8
// baseline (4911.640 us; speedup 1.0000x reference)
//
#include <hip/hip_runtime.h>
#include <hip/hip_bf16.h>
#include <stdint.h>

// GRU fused scan: B=128, T=512, I=H=512.
// 256 wgs x 192 threads (3 waves = gates r,z,n). wg (bgrp=id&7, ugrp=id>>3)
// owns batch rows [bgrp*16,+16) and hidden units [ugrp*16,+16).
// Sync structure = round 6 exactly (proven): agent-scope relaxed atomics for
// h (bf16, double-buffered in d_ws) + one monotonic flag word per wg;
// producer orders h-stores before flag with s_waitcnt vmcnt(0); consumers
// poll 32 flags with all 64 lanes + ballot.
// NEW this round: xs is staged through LDS with COALESCED loads and a
// 2-step prefetch ring (3 buffers). Per step the 16x512 fp32 tile is loaded
// as contiguous float4s by all 192 threads, converted once to bf16
// (v_cvt_pk_bf16_f32, RNE) and ds-written XOR-swizzled; MFMA A-fragments
// come from ds_read_b128. Loads for tile t+2 are issued right after the
// h-loads (HBM latency hides under poll/h-load/MFMA), ds-written just
// before the per-step barrier. This removes the uncoalesced, latency-bound
// xs reads from the serial critical path.

static constexpr int INPUT = 512;
static constexpr int HID   = 512;
static constexpr int NB    = 128;
static constexpr int TLEN  = 512;
static constexpr int BGRPS = 8;
static constexpr int UGRPS = 32;
static constexpr int PD    = 2;    // prefetch depth (steps ahead)
static constexpr int NBUF  = 3;    // LDS tile ring size (> PD: no same-step WAR)

typedef __attribute__((ext_vector_type(4))) float f32x4;
typedef __attribute__((ext_vector_type(8))) short s16x8;

static __device__ __forceinline__ unsigned short f2bf(float f) {
  unsigned u = __builtin_bit_cast(unsigned, f);
  u += 0x7FFFu + ((u >> 16) & 1u);   // RNE
  return (unsigned short)(u >> 16);
}

// 8 consecutive fp32 -> bf16x8 (RNE via packed convert); weights only
static __device__ __forceinline__ s16x8 cvt8(const float* p) {
  f32x4 a = *(const f32x4*)p;
  f32x4 b = *(const f32x4*)(p + 4);
  unsigned r0, r1, r2, r3;
  asm("v_cvt_pk_bf16_f32 %0, %1, %2" : "=v"(r0) : "v"(a[0]), "v"(a[1]));
  asm("v_cvt_pk_bf16_f32 %0, %1, %2" : "=v"(r1) : "v"(a[2]), "v"(a[3]));
  asm("v_cvt_pk_bf16_f32 %0, %1, %2" : "=v"(r2) : "v"(b[0]), "v"(b[1]));
  asm("v_cvt_pk_bf16_f32 %0, %1, %2" : "=v"(r3) : "v"(b[2]), "v"(b[3]));
  union { unsigned u[4]; s16x8 s; } r;
  r.u[0] = r0; r.u[1] = r1; r.u[2] = r2; r.u[3] = r3;
  return r.s;
}

// float4 slot idx (0..2047) of a 16x512 tile -> swizzled LDS byte offset
static __device__ __forceinline__ int tile_byte(int idx) {
  int rw = idx >> 7, c = idx & 127;
  return rw * 1024 + ((c * 8) ^ ((rw & 7) << 4));
}

// convert float4 -> 4 bf16 and store 8B into tile buffer
static __device__ __forceinline__ void st_tile(char* xtb, int idx, f32x4 v) {
  unsigned lo, hi;
  asm("v_cvt_pk_bf16_f32 %0, %1, %2" : "=v"(lo) : "v"(v[0]), "v"(v[1]));
  asm("v_cvt_pk_bf16_f32 %0, %1, %2" : "=v"(hi) : "v"(v[2]), "v"(v[3]));
  union { unsigned u[2]; unsigned long long q; } r;
  r.u[0] = lo; r.u[1] = hi;
  *(unsigned long long*)(xtb + tile_byte(idx)) = r.q;
}

__global__ __launch_bounds__(192, 2) void gru_fused(
    const float* __restrict__ xs, const float* __restrict__ wih,
    const float* __restrict__ whh, const float* __restrict__ bias,
    const float* __restrict__ bias_n, float* __restrict__ out,
    unsigned short* __restrict__ hbuf, unsigned int* __restrict__ flags)
{
  const int wg   = blockIdx.x;
  const int bgrp = wg & 7;
  const int ugrp = wg >> 3;
  const int b0   = bgrp * 16;
  const int u0   = ugrp * 16;
  const int tid  = threadIdx.x;
  const int g    = tid >> 6;      // 0=r, 1=z, 2=n
  const int lane = tid & 63;
  const int ln   = lane & 15;     // unit / batch-row index within tile
  const int kg   = lane >> 4;     // k-octet group 0..3

  __shared__ unsigned short xt[NBUF][16 * 512];   // 48 KB bf16 x-tiles
  __shared__ float xch[2][4][16][16];             // 8 KB gate exchange (dbuf)

  // ---- preload weight fragments into registers (one-time) ----
  const int rowW = g * HID + u0 + ln;
  s16x8 wa[16], wb[16];
#pragma unroll
  for (int ks = 0; ks < 16; ++ks) {
    const int k = ks * 32 + kg * 8;
    wa[ks] = cvt8(wih + (size_t)rowW * INPUT + k);
    wb[ks] = cvt8(whh + (size_t)rowW * HID + k);
  }
  const float bv = bias[rowW];
  const float bn = bias_n[u0 + ln];

  const size_t xbase = (size_t)b0 * TLEN * INPUT;   // + rw*TLEN*INPUT + t*INPUT
  const int hoff = (b0 + ln) * HID + kg * 8;        // ushort offset in one h slot

  // ---- prologue: stage x-tiles for t = 0..PD-1 ----
  for (int p = 0; p < PD; ++p) {
    char* xtb = (char*)&xt[p][0];
#pragma unroll
    for (int k = 0; k < 11; ++k) {
      int idx = tid + k * 192;
      if (idx < 2048) {
        int rw = idx >> 7, c = idx & 127;
        f32x4 v = *(const f32x4*)(xs + xbase + (size_t)rw * TLEN * INPUT +
                                  (size_t)p * INPUT + c * 4);
        st_tile(xtb, idx, v);
      }
    }
  }
  __syncthreads();

  float hold[4] = {0.f, 0.f, 0.f, 0.f};

  for (int t = 0; t < TLEN; ++t) {
    // ---- wait: all 32 wgs of my bgrp have published h[t] (flag >= t) ----
    if (t > 0) {
      const unsigned* fp = &flags[bgrp * UGRPS + (lane & 31)];
      unsigned fv;
      do {
        fv = __hip_atomic_load(fp, __ATOMIC_RELAXED, __HIP_MEMORY_SCOPE_AGENT);
      } while (~__ballot(fv >= (unsigned)t));
      __builtin_amdgcn_sched_barrier(0);   // no hoist of h loads above the wait
    }

    // ---- issue h[t] loads (oldest in vmcnt queue) ----
    const unsigned long long* hb =
        (const unsigned long long*)(hbuf + (size_t)(t & 1) * (NB * HID) + hoff);
    unsigned long long q0[16], q1[16];
#pragma unroll
    for (int ks = 0; ks < 16; ++ks) {
      q0[ks] = __hip_atomic_load(hb + ks * 8,     __ATOMIC_RELAXED, __HIP_MEMORY_SCOPE_AGENT);
      q1[ks] = __hip_atomic_load(hb + ks * 8 + 1, __ATOMIC_RELAXED, __HIP_MEMORY_SCOPE_AGENT);
    }

    // ---- issue coalesced xs loads for tile t+PD (latency hides below) ----
    f32x4 xr[11];
    const bool do_stage = (t + PD < TLEN);
    if (do_stage) {
#pragma unroll
      for (int k = 0; k < 11; ++k) {
        int idx = tid + k * 192;
        if (idx < 2048) {
          int rw = idx >> 7, c = idx & 127;
          xr[k] = *(const f32x4*)(xs + xbase + (size_t)rw * TLEN * INPUT +
                                  (size_t)(t + PD) * INPUT + c * 4);
        }
      }
    }

    // ---- x-side GEMM from LDS tile (overlaps h-load latency) ----
    f32x4 acc_a = {bv, bv, bv, bv};
    {
      const char* xtb = (const char*)&xt[t % NBUF][0];
#pragma unroll
      for (int ks = 0; ks < 16; ++ks) {
        int byte = ln * 1024 + ((ks * 64 + kg * 16) ^ ((ln & 7) << 4));
        s16x8 xa = *(const s16x8*)(xtb + byte);
        acc_a = __builtin_amdgcn_mfma_f32_16x16x32_bf16(xa, wa[ks], acc_a, 0, 0, 0);
      }
    }

    // ---- recurrent GEMM: hg = h[t] @ Whh^T ----
    f32x4 acc_b0 = {0.f, 0.f, 0.f, 0.f}, acc_b1 = {0.f, 0.f, 0.f, 0.f};
#pragma unroll
    for (int ks = 0; ks < 16; ks += 2) {
      union { unsigned long long q[2]; s16x8 s; } ua, ub;
      ua.q[0] = q0[ks];     ua.q[1] = q1[ks];
      ub.q[0] = q0[ks + 1]; ub.q[1] = q1[ks + 1];
      acc_b0 = __builtin_amdgcn_mfma_f32_16x16x32_bf16(ua.s, wb[ks],     acc_b0, 0, 0, 0);
      acc_b1 = __builtin_amdgcn_mfma_f32_16x16x32_bf16(ub.s, wb[ks + 1], acc_b1, 0, 0, 0);
    }
    f32x4 acc_b = acc_b0 + acc_b1;

    // ---- exchange gate pre-activations across the 3 waves (dbuf LDS) ----
    float (*xc)[16][16] = xch[t & 1];
    if (g == 0)      { f32x4 s = acc_a + acc_b; *(f32x4*)&xc[0][ln][kg * 4] = s; }
    else if (g == 1) { f32x4 s = acc_a + acc_b; *(f32x4*)&xc[1][ln][kg * 4] = s; }
    else             { *(f32x4*)&xc[2][ln][kg * 4] = acc_a;
                       *(f32x4*)&xc[3][ln][kg * 4] = acc_b; }

    // ---- stage tile t+PD into ring buffer (WAR-safe: (t+PD)%3 != t%3) ----
    if (do_stage) {
      char* xtb = (char*)&xt[(t + PD) % NBUF][0];
#pragma unroll
      for (int k = 0; k < 11; ++k) {
        int idx = tid + k * 192;
        if (idx < 2048) st_tile(xtb, idx, xr[k]);
      }
    }
    __syncthreads();

    f32x4 Sr  = *(const f32x4*)&xc[0][ln][kg * 4];
    f32x4 Sz  = *(const f32x4*)&xc[1][ln][kg * 4];
    f32x4 Snx = *(const f32x4*)&xc[2][ln][kg * 4];
    f32x4 Snh = *(const f32x4*)&xc[3][ln][kg * 4];

    // ---- gate math (all waves redundantly; keeps h_old in regs everywhere) ----
    float hnew[4];
#pragma unroll
    for (int i = 0; i < 4; ++i) {
      float r = 1.f / (1.f + __expf(-Sr[i]));
      float z = 1.f / (1.f + __expf(-Sz[i]));
      float pre = Snx[i] + r * (Snh[i] + bn);
      float e = __expf(2.f * pre);
      float n = 1.f - 2.f / (e + 1.f);   // tanh, overflow-safe
      hnew[i] = n + z * (hold[i] - n);
      hold[i] = hnew[i];
    }

    if (t == TLEN - 1) {
      if (g == 0) {
#pragma unroll
        for (int i = 0; i < 4; ++i)
          out[(size_t)(b0 + kg * 4 + i) * HID + u0 + ln] = hnew[i];
      }
    } else {
      // ---- publish h[t+1], drain, set flag = t+1 ----
      if (g == 0) {
        unsigned short* hbn = hbuf + (size_t)((t + 1) & 1) * (NB * HID);
#pragma unroll
        for (int i = 0; i < 4; ++i) {
          int v  = (int)f2bf(hnew[i]);
          int o1 = __shfl_xor(v, 1);
          unsigned int p = (unsigned int)(v & 0xffff) | ((unsigned int)(o1 & 0xffff) << 16);
          unsigned int o2 = (unsigned int)__shfl_xor((int)p, 2);
          if ((ln & 3) == 0) {
            unsigned long long q = (unsigned long long)p | ((unsigned long long)o2 << 32);
            __hip_atomic_store(
                (unsigned long long*)(hbn + (size_t)(b0 + kg * 4 + i) * HID + u0 + ln),
                q, __ATOMIC_RELAXED, __HIP_MEMORY_SCOPE_AGENT);
          }
        }
        asm volatile("s_waitcnt vmcnt(0)" ::: "memory");  // h stores at IF
        if (tid == 0)
          __hip_atomic_store(&flags[bgrp * UGRPS + ugrp], (unsigned)(t + 1),
                             __ATOMIC_RELAXED, __HIP_MEMORY_SCOPE_AGENT);
      }
    }
  }
}

extern "C" void kernel_launch(void* const* d_in, const int* in_sizes, int n_in,
                              void* d_out, int out_size, void* d_ws, size_t ws_size,
                              hipStream_t stream) {
  const float* xs     = (const float*)d_in[0];
  const float* wih    = (const float*)d_in[1];
  const float* whh    = (const float*)d_in[2];
  const float* bias   = (const float*)d_in[3];
  const float* bias_n = (const float*)d_in[4];
  float* out = (float*)d_out;

  const size_t hbuf_bytes = (size_t)2 * NB * HID * sizeof(unsigned short); // 256 KB
  const size_t flg_bytes  = (size_t)BGRPS * UGRPS * sizeof(unsigned int);  // 1 KB
  unsigned short* hbuf  = (unsigned short*)d_ws;
  unsigned int*   flags = (unsigned int*)((char*)d_ws + hbuf_bytes);

  hipMemsetAsync(d_ws, 0, hbuf_bytes + flg_bytes, stream);

  gru_fused<<<dim3(BGRPS * UGRPS), dim3(192), 0, stream>>>(
      xs, wih, whh, bias, bias_n, out, hbuf, flags);
}